// Round 18
// baseline (333.958 us; speedup 1.0000x reference)
//
#include <hip/hip_runtime.h>

// LocalAttention P=7 window attention — split-pipeline bf16 MFMA.
// Round 18: consolidate. qkv reverted to the r16 version (r17's m-halving
// was neutral; 3rd failed qkv structure theory -> stop). attn_core gets the
// T14 async-split: all 12 global fragment loads (V,K,Q) issued up front,
// bias staging overlapped under them, V LDS-writes deferred -> ONE latency
// exposure instead of two. out_proj final scatter -> nontemporal.

#define NWIN 2048
#define OUT0 19267584L

typedef __attribute__((ext_vector_type(8))) short bf16x8;
typedef __attribute__((ext_vector_type(4))) float f32x4;

#define MFMA(a, b, c) __builtin_amdgcn_mfma_f32_16x16x32_bf16(a, b, c, 0, 0, 0)

__device__ __forceinline__ unsigned short f2b(float f) {
  unsigned u = __builtin_bit_cast(unsigned, f);
  return (unsigned short)((u + 0x7FFFu + ((u >> 16) & 1u)) >> 16);
}
__device__ __forceinline__ unsigned pk2(float a, float b) {
  return (unsigned)f2b(a) | ((unsigned)f2b(b) << 16);
}
__device__ __forceinline__ float b2f(unsigned short h) {
  unsigned u = ((unsigned)h) << 16;
  return __builtin_bit_cast(float, u);
}

// ---- workspace layout ----
#define OWS_BYTES  (2048L * 8 * 49 * 32 * 2)
#define QKV_BYTES  (32L * 3136 * 256 * 2)
#define Q_OFF      OWS_BYTES
#define K_OFF      (Q_OFF + QKV_BYTES)
#define V_OFF      (K_OFF + QKV_BYTES)
#define WQKV_OFF   (V_OFF + QKV_BYTES)
#define WO_OFF     (WQKV_OFF + 768L * 192 * 2)
#define BIAS_OFF   (WO_OFF + 192L * 256 * 2)

// ================= K0: weight cvt (fragment-ordered) + bias table =================
__global__ __launch_bounds__(256) void prep(
    const float* __restrict__ mask, const float* __restrict__ Wq,
    const float* __restrict__ Wkv, const float* __restrict__ Wo,
    const float* __restrict__ pos,
    unsigned short* __restrict__ wqkvF, unsigned short* __restrict__ woF,
    float* __restrict__ bias)
{
  int gid = blockIdx.x * 256 + threadIdx.x;
  if (gid < 147456) {
    int ti = gid / 12288;
    int r  = gid - ti * 12288;
    int ks = r / 2048;  r -= ks * 2048;
    int mi = r / 512;   r -= mi * 512;
    int lane = r / 8;
    int j = r - lane * 8;
    int e = ti * 64 + mi * 16 + (lane & 15);
    int c = ks * 32 + (lane >> 4) * 8 + j;
    float v = (e < 256) ? Wq[e * 192 + c] : Wkv[(e - 256) * 192 + c];
    wqkvF[gid] = f2b(v);
  } else if (gid < 196608) {
    int i = gid - 147456;
    int T  = i / 4096;
    int r  = i - T * 4096;
    int ks = r / 512;  r -= ks * 512;
    int lane = r / 8;
    int m = r - lane * 8;
    int oc = T * 16 + (lane & 15);
    int c  = ks * 32 + (lane >> 4) * 8 + m;
    woF[i] = f2b(Wo[oc * 256 + c]);
  } else if (gid < 199009) {
    int i = gid - 196608;
    int tq = i / 49, tk = i - tq * 49;
    int r0 = tk / 7 - tq / 7 + 6, r1 = tk % 7 - tq % 7 + 6;
    bias[i] = mask[i] + pos[r0 * 13 + r1];
  }
}

// ================= K1: streaming QKV GEMM (r16 version) =================
__global__ __launch_bounds__(256, 2) void qkv_gemm(
    const float* __restrict__ x, const unsigned short* __restrict__ wqkvF,
    unsigned short* __restrict__ qws, unsigned short* __restrict__ kws,
    unsigned short* __restrict__ vws)
{
  __shared__ __align__(16) unsigned short xs[64 * 200];  // 25600 B
  const int tid = threadIdx.x;
  const int w = tid >> 6, lane = tid & 63;
  const int l15 = lane & 15, lg = lane >> 4;
  const int bi = blockIdx.x / 49;
  const int s0 = (blockIdx.x - bi * 49) * 64;
  const f32x4 zero = {0.f, 0.f, 0.f, 0.f};

  {
    const float* xb = x + (long)bi * 192 * 3136 + s0;
    #pragma unroll
    for (int r = 0; r < 12; ++r) {
      int fid = r * 256 + tid;
      int c = fid >> 4, q4 = fid & 15;
      float4 vv = *(const float4*)(xb + c * 3136 + q4 * 4);
      xs[(q4 * 4 + 0) * 200 + c] = f2b(vv.x);
      xs[(q4 * 4 + 1) * 200 + c] = f2b(vv.y);
      xs[(q4 * 4 + 2) * 200 + c] = f2b(vv.z);
      xs[(q4 * 4 + 3) * 200 + c] = f2b(vv.w);
    }
  }
  __syncthreads();

  #pragma unroll
  for (int i = 0; i < 3; ++i) {
    const int ti = i * 4 + w;
    f32x4 acc[4][4];
    #pragma unroll
    for (int a = 0; a < 4; ++a)
      #pragma unroll
      for (int b = 0; b < 4; ++b) acc[a][b] = zero;

    const unsigned short* wtile = wqkvF + (long)ti * 12288 + lane * 8;
    #pragma unroll
    for (int ks = 0; ks < 6; ++ks) {
      const int kc = ks * 32 + lg * 8;
      bf16x8 a[4], b[4];
      #pragma unroll
      for (int mi = 0; mi < 4; ++mi)
        a[mi] = *(const bf16x8*)(wtile + ks * 2048 + mi * 512);
      #pragma unroll
      for (int ni = 0; ni < 4; ++ni)
        b[ni] = *(const bf16x8*)(xs + (ni * 16 + l15) * 200 + kc);
      #pragma unroll
      for (int mi = 0; mi < 4; ++mi)
        #pragma unroll
        for (int ni = 0; ni < 4; ++ni)
          acc[mi][ni] = MFMA(a[mi], b[ni], acc[mi][ni]);
    }
    unsigned short* dst = (ti < 4) ? qws : (ti < 8) ? kws : vws;
    const int eb = (ti * 64) & 255;
    #pragma unroll
    for (int ni = 0; ni < 4; ++ni) {
      long srow = (long)bi * 3136 + s0 + ni * 16 + l15;
      #pragma unroll
      for (int mi = 0; mi < 4; ++mi) {
        int e0 = eb + mi * 16 + lg * 4;
        uint2 v = {pk2(acc[mi][ni][0], acc[mi][ni][1]),
                   pk2(acc[mi][ni][2], acc[mi][ni][3])};
        *(uint2*)(dst + srow * 256 + e0) = v;
      }
    }
  }
}

// ================= K2: attention core (T14 load-early split) =================
#define PSTRIDE 6272
#define VT_OFF  (4 * PSTRIDE)
#define VTSTRIDE 4608
#define BIAS_LDS (VT_OFF + 4 * VTSTRIDE)
#define LDS_TOT (BIAS_LDS + 2401 * 4)

__global__ __launch_bounds__(256, 4) void attn_core(
    const unsigned short* __restrict__ qws, const unsigned short* __restrict__ kws,
    const unsigned short* __restrict__ vws, const float* __restrict__ bias,
    float* __restrict__ attn_out, unsigned short* __restrict__ o_ws)
{
  __shared__ __align__(16) char lds[LDS_TOT];
  const int tid = threadIdx.x;
  const int w = tid >> 6, lane = tid & 63;
  const int l15 = lane & 15, lg = lane >> 4;
  const int gw = blockIdx.x * 4 + w;
  const int win = gw >> 3, h = gw & 7;
  const int bi = win >> 6, w1 = (win >> 3) & 7, w2 = win & 7;
  const int sw = (w1 * 7) * 56 + w2 * 7;
  const long rowbase = (long)bi * 3136;
  const f32x4 zero = {0.f, 0.f, 0.f, 0.f};

  // ---- Phase A: issue ALL 12 global fragment loads up front (T14) ----
  bf16x8 vv[4];
  {
    const int e8 = (lane & 3) * 8;
    #pragma unroll
    for (int pass = 0; pass < 4; ++pass) {
      int t = pass * 16 + (lane >> 2);
      int tc = t < 49 ? t : 48;
      int srow = sw + (tc / 7) * 56 + (tc % 7);
      vv[pass] = *(const bf16x8*)(vws + (rowbase + srow) * 256 + h * 32 + e8);
    }
  }
  bf16x8 ak[4], bq[4];
  {
    const int dc = h * 32 + lg * 8;
    #pragma unroll
    for (int mi = 0; mi < 4; ++mi) {
      int t = mi * 16 + l15; if (t > 48) t = 48;
      int srow = sw + (t / 7) * 56 + (t % 7);
      ak[mi] = *(const bf16x8*)(kws + (rowbase + srow) * 256 + dc);
    }
    #pragma unroll
    for (int ni = 0; ni < 4; ++ni) {
      int t = ni * 16 + l15; if (t > 48) t = 48;
      int srow = sw + (t / 7) * 56 + (t % 7);
      bq[ni] = *(const bf16x8*)(qws + (rowbase + srow) * 256 + dc);
    }
  }

  // ---- bias staging overlaps the in-flight loads ----
  float* bias_lds = (float*)(lds + BIAS_LDS);
  for (int i = tid; i < 2401; i += 256) bias_lds[i] = bias[i];

  // ---- V LDS writes (waits only on vv) ----
  unsigned short* vt = (unsigned short*)(lds + VT_OFF + w * VTSTRIDE);
  {
    const int e8 = (lane & 3) * 8;
    #pragma unroll
    for (int pass = 0; pass < 4; ++pass) {
      int t = pass * 16 + (lane >> 2);
      #pragma unroll
      for (int j = 0; j < 8; ++j) vt[(e8 + j) * 72 + t] = vv[pass][j];
    }
  }
  __syncthreads();  // bias_lds ready (vt is wave-private, ordered by lgkmcnt)

  // ---- S = K.Q^T ----
  f32x4 s[4][4];
  {
    __builtin_amdgcn_s_setprio(1);
    #pragma unroll
    for (int mi = 0; mi < 4; ++mi)
      #pragma unroll
      for (int ni = 0; ni < 4; ++ni)
        s[mi][ni] = MFMA(ak[mi], bq[ni], zero);
    __builtin_amdgcn_s_setprio(0);
  }

  // ---- softmax over tk per tq-column (bias from LDS) ----
  const float scale = 0.17677669529663687f;
  #pragma unroll
  for (int ni = 0; ni < 4; ++ni) {
    int tq = ni * 16 + l15;
    int tqc = tq < 49 ? tq : 48;
    #pragma unroll
    for (int mi = 0; mi < 4; ++mi)
      #pragma unroll
      for (int r = 0; r < 4; ++r) {
        int tk = mi * 16 + lg * 4 + r;
        float v = s[mi][ni][r];
        s[mi][ni][r] = (tk < 49) ? (v * scale + bias_lds[tqc * 49 + tk]) : -1e30f;
      }
    float m = -1e30f;
    #pragma unroll
    for (int mi = 0; mi < 4; ++mi)
      #pragma unroll
      for (int r = 0; r < 4; ++r) m = fmaxf(m, s[mi][ni][r]);
    m = fmaxf(m, __shfl_xor(m, 16));
    m = fmaxf(m, __shfl_xor(m, 32));
    float sum = 0.f;
    #pragma unroll
    for (int mi = 0; mi < 4; ++mi)
      #pragma unroll
      for (int r = 0; r < 4; ++r) {
        float e = __expf(s[mi][ni][r] - m);
        s[mi][ni][r] = e;
        sum += e;
      }
    sum += __shfl_xor(sum, 16);
    sum += __shfl_xor(sum, 32);
    float inv = 1.0f / sum;
    #pragma unroll
    for (int mi = 0; mi < 4; ++mi)
      #pragma unroll
      for (int r = 0; r < 4; ++r) s[mi][ni][r] *= inv;
  }

  // ---- P -> wave-private LDS (bf16, swizzled) ----
  char* pw = lds + w * PSTRIDE;
  #pragma unroll
  for (int ni = 0; ni < 4; ++ni) {
    int tq = ni * 16 + l15;
    if (tq < 49) {
      #pragma unroll
      for (int mi = 0; mi < 4; ++mi) {
        int tk0 = mi * 16 + lg * 4;
        uint2 v = {pk2(s[mi][ni][0], s[mi][ni][1]),
                   pk2(s[mi][ni][2], s[mi][ni][3])};
        *(uint2*)(pw + tq * 128 + ((tk0 * 2) ^ ((tq & 7) << 4))) = v;
      }
    }
  }

  // ---- attn out: coalesced nontemporal stream (overlaps PV) ----
  {
    float* abase = attn_out + ((long)win * 8 + h) * 2401;
    #pragma unroll
    for (int it = 0; it < 38; ++it) {
      int f = it * 64 + lane;
      if (f < 2401) {
        int tq = f / 49, tk = f - tq * 49;
        unsigned short pv =
            *(const unsigned short*)(pw + tq * 128 + ((tk * 2) ^ ((tq & 7) << 4)));
        __builtin_nontemporal_store(b2f(pv), abase + f);
      }
    }
  }

  // ---- O = Vt.P^T -> o_ws ----
  {
    f32x4 o[2][4];
    #pragma unroll
    for (int i = 0; i < 2; ++i)
      #pragma unroll
      for (int j = 0; j < 4; ++j) o[i][j] = zero;
    #pragma unroll
    for (int ks = 0; ks < 2; ++ks) {
      const int tkc = ks * 32 + lg * 8;
      bf16x8 av[2], bp[4];
      #pragma unroll
      for (int mi = 0; mi < 2; ++mi) {
        int e = mi * 16 + l15;
        av[mi] = *(const bf16x8*)(vt + e * 72 + tkc);
      }
      #pragma unroll
      for (int ni = 0; ni < 4; ++ni) {
        int tq = ni * 16 + l15;
        int tqc = tq < 49 ? tq : 48;
        bp[ni] = *(const bf16x8*)(pw + tqc * 128 + ((tkc * 2) ^ ((tqc & 7) << 4)));
      }
      __builtin_amdgcn_s_setprio(1);
      #pragma unroll
      for (int mi = 0; mi < 2; ++mi)
        #pragma unroll
        for (int ni = 0; ni < 4; ++ni)
          o[mi][ni] = MFMA(av[mi], bp[ni], o[mi][ni]);
      __builtin_amdgcn_s_setprio(0);
    }
    unsigned short* ob = o_ws + ((long)win * 8 + h) * 49 * 32;
    #pragma unroll
    for (int mi = 0; mi < 2; ++mi)
      #pragma unroll
      for (int ni = 0; ni < 4; ++ni) {
        int tq = ni * 16 + l15;
        if (tq < 49) {
          int el0 = mi * 16 + lg * 4;
          uint2 v = {pk2(o[mi][ni][0], o[mi][ni][1]),
                     pk2(o[mi][ni][2], o[mi][ni][3])};
          *(uint2*)(ob + tq * 32 + el0) = v;
        }
      }
  }
}

// ================= K3: output projection (r16 + NT scatter) =================
__global__ __launch_bounds__(256, 8) void out_proj(
    const unsigned short* __restrict__ o_ws, const unsigned short* __restrict__ woF,
    const float* __restrict__ bo, float* __restrict__ out)
{
  __shared__ __align__(16) float obuf[49 * 196];
  const int tid = threadIdx.x;
  const int w = tid >> 6, lane = tid & 63;
  const int l15 = lane & 15, lg = lane >> 4;
  const int win = blockIdx.x;
  const int bi = win >> 6, w1 = (win >> 3) & 7, w2 = win & 7;
  const f32x4 zero = {0.f, 0.f, 0.f, 0.f};

  const unsigned short* wt = woF + (long)(w * 3) * 4096 + lane * 8;

  #pragma unroll
  for (int pass = 0; pass < 2; ++pass) {
    f32x4 acc[3][2];
    #pragma unroll
    for (int j = 0; j < 3; ++j)
      #pragma unroll
      for (int tt = 0; tt < 2; ++tt) acc[j][tt] = zero;

    #pragma unroll
    for (int ks = 0; ks < 8; ++ks) {
      bf16x8 aW[3], bO[2];
      #pragma unroll
      for (int j = 0; j < 3; ++j)
        aW[j] = *(const bf16x8*)(wt + j * 4096 + ks * 512);
      #pragma unroll
      for (int tt = 0; tt < 2; ++tt) {
        int t = (pass * 2 + tt) * 16 + l15;
        int tc = t < 49 ? t : 48;
        bO[tt] = *(const bf16x8*)(o_ws + ((long)(win * 8 + ks) * 49 + tc) * 32 + lg * 8);
      }
      #pragma unroll
      for (int j = 0; j < 3; ++j)
        #pragma unroll
        for (int tt = 0; tt < 2; ++tt)
          acc[j][tt] = MFMA(aW[j], bO[tt], acc[j][tt]);
    }
    #pragma unroll
    for (int j = 0; j < 3; ++j)
      #pragma unroll
      for (int tt = 0; tt < 2; ++tt) {
        int t = (pass * 2 + tt) * 16 + l15;
        if (t < 49) {
          int oc0 = (w * 3 + j) * 16 + lg * 4;
          *(f32x4*)(obuf + t * 196 + oc0) = acc[j][tt];
        }
      }
  }
  __syncthreads();

  const long obase = (long)bi * 602112 + (w1 * 7) * 56 + w2 * 7;
  for (int idx = tid; idx < 192 * 49; idx += 256) {
    int oc = idx / 49, t = idx - oc * 49;
    __builtin_nontemporal_store(obuf[t * 196 + oc] + bo[oc],
                                &out[obase + oc * 3136 + (t / 7) * 56 + (t % 7)]);
  }
}

extern "C" void kernel_launch(void* const* d_in, const int* in_sizes, int n_in,
                              void* d_out, int out_size, void* d_ws, size_t ws_size,
                              hipStream_t stream)
{
  const float* x    = (const float*)d_in[0];
  const float* mask = (const float*)d_in[1];
  const float* Wq   = (const float*)d_in[2];
  const float* Wkv  = (const float*)d_in[3];
  const float* Wo   = (const float*)d_in[4];
  const float* bo   = (const float*)d_in[5];
  const float* pos  = (const float*)d_in[6];

  float* out  = (float*)d_out;
  float* attn = out + OUT0;

  char* ws = (char*)d_ws;
  unsigned short* o_ws = (unsigned short*)ws;
  unsigned short* qws  = (unsigned short*)(ws + Q_OFF);
  unsigned short* kws  = (unsigned short*)(ws + K_OFF);
  unsigned short* vws  = (unsigned short*)(ws + V_OFF);
  unsigned short* wqkv = (unsigned short*)(ws + WQKV_OFF);
  unsigned short* woF  = (unsigned short*)(ws + WO_OFF);
  float*          bias = (float*)(ws + BIAS_OFF);

  prep<<<778, 256, 0, stream>>>(mask, Wq, Wkv, Wo, pos, wqkv, woF, bias);
  qkv_gemm<<<32 * 49, 256, 0, stream>>>(x, wqkv, qws, kws, vws);
  attn_core<<<4096, 256, 0, stream>>>(qws, kws, vws, bias, attn, o_ws);
  out_proj<<<NWIN, 256, 0, stream>>>(o_ws, woF, bo, out);
}

// Round 19
// 266.436 us; speedup vs baseline: 1.2534x; 1.2534x over previous
//
#include <hip/hip_runtime.h>

// LocalAttention P=7 window attention — split-pipeline bf16 MFMA.
// Round 19: revert out_proj's nontemporal scatter (r18's regression:
// NT bypasses L2 write-merging, so the 28B-run scatter became per-line
// RMW -> WRITE_SIZE 112->157MB, out_proj 55->165us). NT stays ONLY on
// attn_core's full-line stream. attn_core keeps r18's T14 load-early
// split. prep / qkv_gemm unchanged (r16 versions).

#define NWIN 2048
#define OUT0 19267584L

typedef __attribute__((ext_vector_type(8))) short bf16x8;
typedef __attribute__((ext_vector_type(4))) float f32x4;

#define MFMA(a, b, c) __builtin_amdgcn_mfma_f32_16x16x32_bf16(a, b, c, 0, 0, 0)

__device__ __forceinline__ unsigned short f2b(float f) {
  unsigned u = __builtin_bit_cast(unsigned, f);
  return (unsigned short)((u + 0x7FFFu + ((u >> 16) & 1u)) >> 16);
}
__device__ __forceinline__ unsigned pk2(float a, float b) {
  return (unsigned)f2b(a) | ((unsigned)f2b(b) << 16);
}
__device__ __forceinline__ float b2f(unsigned short h) {
  unsigned u = ((unsigned)h) << 16;
  return __builtin_bit_cast(float, u);
}

// ---- workspace layout ----
#define OWS_BYTES  (2048L * 8 * 49 * 32 * 2)
#define QKV_BYTES  (32L * 3136 * 256 * 2)
#define Q_OFF      OWS_BYTES
#define K_OFF      (Q_OFF + QKV_BYTES)
#define V_OFF      (K_OFF + QKV_BYTES)
#define WQKV_OFF   (V_OFF + QKV_BYTES)
#define WO_OFF     (WQKV_OFF + 768L * 192 * 2)
#define BIAS_OFF   (WO_OFF + 192L * 256 * 2)

// ================= K0: weight cvt (fragment-ordered) + bias table =================
__global__ __launch_bounds__(256) void prep(
    const float* __restrict__ mask, const float* __restrict__ Wq,
    const float* __restrict__ Wkv, const float* __restrict__ Wo,
    const float* __restrict__ pos,
    unsigned short* __restrict__ wqkvF, unsigned short* __restrict__ woF,
    float* __restrict__ bias)
{
  int gid = blockIdx.x * 256 + threadIdx.x;
  if (gid < 147456) {
    int ti = gid / 12288;
    int r  = gid - ti * 12288;
    int ks = r / 2048;  r -= ks * 2048;
    int mi = r / 512;   r -= mi * 512;
    int lane = r / 8;
    int j = r - lane * 8;
    int e = ti * 64 + mi * 16 + (lane & 15);
    int c = ks * 32 + (lane >> 4) * 8 + j;
    float v = (e < 256) ? Wq[e * 192 + c] : Wkv[(e - 256) * 192 + c];
    wqkvF[gid] = f2b(v);
  } else if (gid < 196608) {
    int i = gid - 147456;
    int T  = i / 4096;
    int r  = i - T * 4096;
    int ks = r / 512;  r -= ks * 512;
    int lane = r / 8;
    int m = r - lane * 8;
    int oc = T * 16 + (lane & 15);
    int c  = ks * 32 + (lane >> 4) * 8 + m;
    woF[i] = f2b(Wo[oc * 256 + c]);
  } else if (gid < 199009) {
    int i = gid - 196608;
    int tq = i / 49, tk = i - tq * 49;
    int r0 = tk / 7 - tq / 7 + 6, r1 = tk % 7 - tq % 7 + 6;
    bias[i] = mask[i] + pos[r0 * 13 + r1];
  }
}

// ================= K1: streaming QKV GEMM (r16 version) =================
__global__ __launch_bounds__(256, 2) void qkv_gemm(
    const float* __restrict__ x, const unsigned short* __restrict__ wqkvF,
    unsigned short* __restrict__ qws, unsigned short* __restrict__ kws,
    unsigned short* __restrict__ vws)
{
  __shared__ __align__(16) unsigned short xs[64 * 200];  // 25600 B
  const int tid = threadIdx.x;
  const int w = tid >> 6, lane = tid & 63;
  const int l15 = lane & 15, lg = lane >> 4;
  const int bi = blockIdx.x / 49;
  const int s0 = (blockIdx.x - bi * 49) * 64;
  const f32x4 zero = {0.f, 0.f, 0.f, 0.f};

  {
    const float* xb = x + (long)bi * 192 * 3136 + s0;
    #pragma unroll
    for (int r = 0; r < 12; ++r) {
      int fid = r * 256 + tid;
      int c = fid >> 4, q4 = fid & 15;
      float4 vv = *(const float4*)(xb + c * 3136 + q4 * 4);
      xs[(q4 * 4 + 0) * 200 + c] = f2b(vv.x);
      xs[(q4 * 4 + 1) * 200 + c] = f2b(vv.y);
      xs[(q4 * 4 + 2) * 200 + c] = f2b(vv.z);
      xs[(q4 * 4 + 3) * 200 + c] = f2b(vv.w);
    }
  }
  __syncthreads();

  #pragma unroll
  for (int i = 0; i < 3; ++i) {
    const int ti = i * 4 + w;
    f32x4 acc[4][4];
    #pragma unroll
    for (int a = 0; a < 4; ++a)
      #pragma unroll
      for (int b = 0; b < 4; ++b) acc[a][b] = zero;

    const unsigned short* wtile = wqkvF + (long)ti * 12288 + lane * 8;
    #pragma unroll
    for (int ks = 0; ks < 6; ++ks) {
      const int kc = ks * 32 + lg * 8;
      bf16x8 a[4], b[4];
      #pragma unroll
      for (int mi = 0; mi < 4; ++mi)
        a[mi] = *(const bf16x8*)(wtile + ks * 2048 + mi * 512);
      #pragma unroll
      for (int ni = 0; ni < 4; ++ni)
        b[ni] = *(const bf16x8*)(xs + (ni * 16 + l15) * 200 + kc);
      #pragma unroll
      for (int mi = 0; mi < 4; ++mi)
        #pragma unroll
        for (int ni = 0; ni < 4; ++ni)
          acc[mi][ni] = MFMA(a[mi], b[ni], acc[mi][ni]);
    }
    unsigned short* dst = (ti < 4) ? qws : (ti < 8) ? kws : vws;
    const int eb = (ti * 64) & 255;
    #pragma unroll
    for (int ni = 0; ni < 4; ++ni) {
      long srow = (long)bi * 3136 + s0 + ni * 16 + l15;
      #pragma unroll
      for (int mi = 0; mi < 4; ++mi) {
        int e0 = eb + mi * 16 + lg * 4;
        uint2 v = {pk2(acc[mi][ni][0], acc[mi][ni][1]),
                   pk2(acc[mi][ni][2], acc[mi][ni][3])};
        *(uint2*)(dst + srow * 256 + e0) = v;
      }
    }
  }
}

// ================= K2: attention core (T14 load-early split) =================
#define PSTRIDE 6272
#define VT_OFF  (4 * PSTRIDE)
#define VTSTRIDE 4608
#define BIAS_LDS (VT_OFF + 4 * VTSTRIDE)
#define LDS_TOT (BIAS_LDS + 2401 * 4)

__global__ __launch_bounds__(256, 4) void attn_core(
    const unsigned short* __restrict__ qws, const unsigned short* __restrict__ kws,
    const unsigned short* __restrict__ vws, const float* __restrict__ bias,
    float* __restrict__ attn_out, unsigned short* __restrict__ o_ws)
{
  __shared__ __align__(16) char lds[LDS_TOT];
  const int tid = threadIdx.x;
  const int w = tid >> 6, lane = tid & 63;
  const int l15 = lane & 15, lg = lane >> 4;
  const int gw = blockIdx.x * 4 + w;
  const int win = gw >> 3, h = gw & 7;
  const int bi = win >> 6, w1 = (win >> 3) & 7, w2 = win & 7;
  const int sw = (w1 * 7) * 56 + w2 * 7;
  const long rowbase = (long)bi * 3136;
  const f32x4 zero = {0.f, 0.f, 0.f, 0.f};

  // ---- Phase A: issue ALL 12 global fragment loads up front (T14) ----
  bf16x8 vv[4];
  {
    const int e8 = (lane & 3) * 8;
    #pragma unroll
    for (int pass = 0; pass < 4; ++pass) {
      int t = pass * 16 + (lane >> 2);
      int tc = t < 49 ? t : 48;
      int srow = sw + (tc / 7) * 56 + (tc % 7);
      vv[pass] = *(const bf16x8*)(vws + (rowbase + srow) * 256 + h * 32 + e8);
    }
  }
  bf16x8 ak[4], bq[4];
  {
    const int dc = h * 32 + lg * 8;
    #pragma unroll
    for (int mi = 0; mi < 4; ++mi) {
      int t = mi * 16 + l15; if (t > 48) t = 48;
      int srow = sw + (t / 7) * 56 + (t % 7);
      ak[mi] = *(const bf16x8*)(kws + (rowbase + srow) * 256 + dc);
    }
    #pragma unroll
    for (int ni = 0; ni < 4; ++ni) {
      int t = ni * 16 + l15; if (t > 48) t = 48;
      int srow = sw + (t / 7) * 56 + (t % 7);
      bq[ni] = *(const bf16x8*)(qws + (rowbase + srow) * 256 + dc);
    }
  }

  // ---- bias staging overlaps the in-flight loads ----
  float* bias_lds = (float*)(lds + BIAS_LDS);
  for (int i = tid; i < 2401; i += 256) bias_lds[i] = bias[i];

  // ---- V LDS writes (waits only on vv) ----
  unsigned short* vt = (unsigned short*)(lds + VT_OFF + w * VTSTRIDE);
  {
    const int e8 = (lane & 3) * 8;
    #pragma unroll
    for (int pass = 0; pass < 4; ++pass) {
      int t = pass * 16 + (lane >> 2);
      #pragma unroll
      for (int j = 0; j < 8; ++j) vt[(e8 + j) * 72 + t] = vv[pass][j];
    }
  }
  __syncthreads();  // bias_lds ready (vt is wave-private, ordered by lgkmcnt)

  // ---- S = K.Q^T ----
  f32x4 s[4][4];
  {
    __builtin_amdgcn_s_setprio(1);
    #pragma unroll
    for (int mi = 0; mi < 4; ++mi)
      #pragma unroll
      for (int ni = 0; ni < 4; ++ni)
        s[mi][ni] = MFMA(ak[mi], bq[ni], zero);
    __builtin_amdgcn_s_setprio(0);
  }

  // ---- softmax over tk per tq-column (bias from LDS) ----
  const float scale = 0.17677669529663687f;
  #pragma unroll
  for (int ni = 0; ni < 4; ++ni) {
    int tq = ni * 16 + l15;
    int tqc = tq < 49 ? tq : 48;
    #pragma unroll
    for (int mi = 0; mi < 4; ++mi)
      #pragma unroll
      for (int r = 0; r < 4; ++r) {
        int tk = mi * 16 + lg * 4 + r;
        float v = s[mi][ni][r];
        s[mi][ni][r] = (tk < 49) ? (v * scale + bias_lds[tqc * 49 + tk]) : -1e30f;
      }
    float m = -1e30f;
    #pragma unroll
    for (int mi = 0; mi < 4; ++mi)
      #pragma unroll
      for (int r = 0; r < 4; ++r) m = fmaxf(m, s[mi][ni][r]);
    m = fmaxf(m, __shfl_xor(m, 16));
    m = fmaxf(m, __shfl_xor(m, 32));
    float sum = 0.f;
    #pragma unroll
    for (int mi = 0; mi < 4; ++mi)
      #pragma unroll
      for (int r = 0; r < 4; ++r) {
        float e = __expf(s[mi][ni][r] - m);
        s[mi][ni][r] = e;
        sum += e;
      }
    sum += __shfl_xor(sum, 16);
    sum += __shfl_xor(sum, 32);
    float inv = 1.0f / sum;
    #pragma unroll
    for (int mi = 0; mi < 4; ++mi)
      #pragma unroll
      for (int r = 0; r < 4; ++r) s[mi][ni][r] *= inv;
  }

  // ---- P -> wave-private LDS (bf16, swizzled) ----
  char* pw = lds + w * PSTRIDE;
  #pragma unroll
  for (int ni = 0; ni < 4; ++ni) {
    int tq = ni * 16 + l15;
    if (tq < 49) {
      #pragma unroll
      for (int mi = 0; mi < 4; ++mi) {
        int tk0 = mi * 16 + lg * 4;
        uint2 v = {pk2(s[mi][ni][0], s[mi][ni][1]),
                   pk2(s[mi][ni][2], s[mi][ni][3])};
        *(uint2*)(pw + tq * 128 + ((tk0 * 2) ^ ((tq & 7) << 4))) = v;
      }
    }
  }

  // ---- attn out: coalesced nontemporal stream (full lines; overlaps PV) ----
  {
    float* abase = attn_out + ((long)win * 8 + h) * 2401;
    #pragma unroll
    for (int it = 0; it < 38; ++it) {
      int f = it * 64 + lane;
      if (f < 2401) {
        int tq = f / 49, tk = f - tq * 49;
        unsigned short pv =
            *(const unsigned short*)(pw + tq * 128 + ((tk * 2) ^ ((tq & 7) << 4)));
        __builtin_nontemporal_store(b2f(pv), abase + f);
      }
    }
  }

  // ---- O = Vt.P^T -> o_ws ----
  {
    f32x4 o[2][4];
    #pragma unroll
    for (int i = 0; i < 2; ++i)
      #pragma unroll
      for (int j = 0; j < 4; ++j) o[i][j] = zero;
    #pragma unroll
    for (int ks = 0; ks < 2; ++ks) {
      const int tkc = ks * 32 + lg * 8;
      bf16x8 av[2], bp[4];
      #pragma unroll
      for (int mi = 0; mi < 2; ++mi) {
        int e = mi * 16 + l15;
        av[mi] = *(const bf16x8*)(vt + e * 72 + tkc);
      }
      #pragma unroll
      for (int ni = 0; ni < 4; ++ni) {
        int tq = ni * 16 + l15;
        int tqc = tq < 49 ? tq : 48;
        bp[ni] = *(const bf16x8*)(pw + tqc * 128 + ((tkc * 2) ^ ((tqc & 7) << 4)));
      }
      __builtin_amdgcn_s_setprio(1);
      #pragma unroll
      for (int mi = 0; mi < 2; ++mi)
        #pragma unroll
        for (int ni = 0; ni < 4; ++ni)
          o[mi][ni] = MFMA(av[mi], bp[ni], o[mi][ni]);
      __builtin_amdgcn_s_setprio(0);
    }
    unsigned short* ob = o_ws + ((long)win * 8 + h) * 49 * 32;
    #pragma unroll
    for (int mi = 0; mi < 2; ++mi)
      #pragma unroll
      for (int ni = 0; ni < 4; ++ni) {
        int tq = ni * 16 + l15;
        if (tq < 49) {
          int el0 = mi * 16 + lg * 4;
          uint2 v = {pk2(o[mi][ni][0], o[mi][ni][1]),
                     pk2(o[mi][ni][2], o[mi][ni][3])};
          *(uint2*)(ob + tq * 32 + el0) = v;
        }
      }
  }
}

// ================= K3: output projection (r16 version, regular stores) =================
__global__ __launch_bounds__(256, 8) void out_proj(
    const unsigned short* __restrict__ o_ws, const unsigned short* __restrict__ woF,
    const float* __restrict__ bo, float* __restrict__ out)
{
  __shared__ __align__(16) float obuf[49 * 196];
  const int tid = threadIdx.x;
  const int w = tid >> 6, lane = tid & 63;
  const int l15 = lane & 15, lg = lane >> 4;
  const int win = blockIdx.x;
  const int bi = win >> 6, w1 = (win >> 3) & 7, w2 = win & 7;
  const f32x4 zero = {0.f, 0.f, 0.f, 0.f};

  const unsigned short* wt = woF + (long)(w * 3) * 4096 + lane * 8;

  #pragma unroll
  for (int pass = 0; pass < 2; ++pass) {
    f32x4 acc[3][2];
    #pragma unroll
    for (int j = 0; j < 3; ++j)
      #pragma unroll
      for (int tt = 0; tt < 2; ++tt) acc[j][tt] = zero;

    #pragma unroll
    for (int ks = 0; ks < 8; ++ks) {
      bf16x8 aW[3], bO[2];
      #pragma unroll
      for (int j = 0; j < 3; ++j)
        aW[j] = *(const bf16x8*)(wt + j * 4096 + ks * 512);
      #pragma unroll
      for (int tt = 0; tt < 2; ++tt) {
        int t = (pass * 2 + tt) * 16 + l15;
        int tc = t < 49 ? t : 48;
        bO[tt] = *(const bf16x8*)(o_ws + ((long)(win * 8 + ks) * 49 + tc) * 32 + lg * 8);
      }
      #pragma unroll
      for (int j = 0; j < 3; ++j)
        #pragma unroll
        for (int tt = 0; tt < 2; ++tt)
          acc[j][tt] = MFMA(aW[j], bO[tt], acc[j][tt]);
    }
    #pragma unroll
    for (int j = 0; j < 3; ++j)
      #pragma unroll
      for (int tt = 0; tt < 2; ++tt) {
        int t = (pass * 2 + tt) * 16 + l15;
        if (t < 49) {
          int oc0 = (w * 3 + j) * 16 + lg * 4;
          *(f32x4*)(obuf + t * 196 + oc0) = acc[j][tt];
        }
      }
  }
  __syncthreads();

  const long obase = (long)bi * 602112 + (w1 * 7) * 56 + w2 * 7;
  for (int idx = tid; idx < 192 * 49; idx += 256) {
    int oc = idx / 49, t = idx - oc * 49;
    out[obase + oc * 3136 + (t / 7) * 56 + (t % 7)] = obuf[t * 196 + oc] + bo[oc];
  }
}

extern "C" void kernel_launch(void* const* d_in, const int* in_sizes, int n_in,
                              void* d_out, int out_size, void* d_ws, size_t ws_size,
                              hipStream_t stream)
{
  const float* x    = (const float*)d_in[0];
  const float* mask = (const float*)d_in[1];
  const float* Wq   = (const float*)d_in[2];
  const float* Wkv  = (const float*)d_in[3];
  const float* Wo   = (const float*)d_in[4];
  const float* bo   = (const float*)d_in[5];
  const float* pos  = (const float*)d_in[6];

  float* out  = (float*)d_out;
  float* attn = out + OUT0;

  char* ws = (char*)d_ws;
  unsigned short* o_ws = (unsigned short*)ws;
  unsigned short* qws  = (unsigned short*)(ws + Q_OFF);
  unsigned short* kws  = (unsigned short*)(ws + K_OFF);
  unsigned short* vws  = (unsigned short*)(ws + V_OFF);
  unsigned short* wqkv = (unsigned short*)(ws + WQKV_OFF);
  unsigned short* woF  = (unsigned short*)(ws + WO_OFF);
  float*          bias = (float*)(ws + BIAS_OFF);

  prep<<<778, 256, 0, stream>>>(mask, Wq, Wkv, Wo, pos, wqkv, woF, bias);
  qkv_gemm<<<32 * 49, 256, 0, stream>>>(x, wqkv, qws, kws, vws);
  attn_core<<<4096, 256, 0, stream>>>(qws, kws, vws, bias, attn, o_ws);
  out_proj<<<NWIN, 256, 0, stream>>>(o_ws, woF, bo, out);
}

// Round 20
// 253.636 us; speedup vs baseline: 1.3167x; 1.0505x over previous
//
#include <hip/hip_runtime.h>

// LocalAttention P=7 window attention — split-pipeline bf16 MFMA.
// Round 20: exact re-pin of the round-16 best (255us). r19 showed the T14
// load-early split in attn_core was a small real regression (+11us; 48
// extra live VGPRs through bias staging), so attn_core reverts to r16:
// V-stage->LDS, bias-LDS, setprio on MFMA clusters, NT only on the
// full-line attn stream. qkv/out_proj/prep are r16 already.

#define NWIN 2048
#define OUT0 19267584L

typedef __attribute__((ext_vector_type(8))) short bf16x8;
typedef __attribute__((ext_vector_type(4))) float f32x4;

#define MFMA(a, b, c) __builtin_amdgcn_mfma_f32_16x16x32_bf16(a, b, c, 0, 0, 0)

__device__ __forceinline__ unsigned short f2b(float f) {
  unsigned u = __builtin_bit_cast(unsigned, f);
  return (unsigned short)((u + 0x7FFFu + ((u >> 16) & 1u)) >> 16);
}
__device__ __forceinline__ unsigned pk2(float a, float b) {
  return (unsigned)f2b(a) | ((unsigned)f2b(b) << 16);
}
__device__ __forceinline__ float b2f(unsigned short h) {
  unsigned u = ((unsigned)h) << 16;
  return __builtin_bit_cast(float, u);
}

// ---- workspace layout ----
#define OWS_BYTES  (2048L * 8 * 49 * 32 * 2)
#define QKV_BYTES  (32L * 3136 * 256 * 2)
#define Q_OFF      OWS_BYTES
#define K_OFF      (Q_OFF + QKV_BYTES)
#define V_OFF      (K_OFF + QKV_BYTES)
#define WQKV_OFF   (V_OFF + QKV_BYTES)
#define WO_OFF     (WQKV_OFF + 768L * 192 * 2)
#define BIAS_OFF   (WO_OFF + 192L * 256 * 2)

// ================= K0: weight cvt (fragment-ordered) + bias table =================
__global__ __launch_bounds__(256) void prep(
    const float* __restrict__ mask, const float* __restrict__ Wq,
    const float* __restrict__ Wkv, const float* __restrict__ Wo,
    const float* __restrict__ pos,
    unsigned short* __restrict__ wqkvF, unsigned short* __restrict__ woF,
    float* __restrict__ bias)
{
  int gid = blockIdx.x * 256 + threadIdx.x;
  if (gid < 147456) {
    int ti = gid / 12288;
    int r  = gid - ti * 12288;
    int ks = r / 2048;  r -= ks * 2048;
    int mi = r / 512;   r -= mi * 512;
    int lane = r / 8;
    int j = r - lane * 8;
    int e = ti * 64 + mi * 16 + (lane & 15);
    int c = ks * 32 + (lane >> 4) * 8 + j;
    float v = (e < 256) ? Wq[e * 192 + c] : Wkv[(e - 256) * 192 + c];
    wqkvF[gid] = f2b(v);
  } else if (gid < 196608) {
    int i = gid - 147456;
    int T  = i / 4096;
    int r  = i - T * 4096;
    int ks = r / 512;  r -= ks * 512;
    int lane = r / 8;
    int m = r - lane * 8;
    int oc = T * 16 + (lane & 15);
    int c  = ks * 32 + (lane >> 4) * 8 + m;
    woF[i] = f2b(Wo[oc * 256 + c]);
  } else if (gid < 199009) {
    int i = gid - 196608;
    int tq = i / 49, tk = i - tq * 49;
    int r0 = tk / 7 - tq / 7 + 6, r1 = tk % 7 - tq % 7 + 6;
    bias[i] = mask[i] + pos[r0 * 13 + r1];
  }
}

// ================= K1: streaming QKV GEMM =================
__global__ __launch_bounds__(256, 2) void qkv_gemm(
    const float* __restrict__ x, const unsigned short* __restrict__ wqkvF,
    unsigned short* __restrict__ qws, unsigned short* __restrict__ kws,
    unsigned short* __restrict__ vws)
{
  __shared__ __align__(16) unsigned short xs[64 * 200];  // 25600 B
  const int tid = threadIdx.x;
  const int w = tid >> 6, lane = tid & 63;
  const int l15 = lane & 15, lg = lane >> 4;
  const int bi = blockIdx.x / 49;
  const int s0 = (blockIdx.x - bi * 49) * 64;
  const f32x4 zero = {0.f, 0.f, 0.f, 0.f};

  {
    const float* xb = x + (long)bi * 192 * 3136 + s0;
    #pragma unroll
    for (int r = 0; r < 12; ++r) {
      int fid = r * 256 + tid;
      int c = fid >> 4, q4 = fid & 15;
      float4 vv = *(const float4*)(xb + c * 3136 + q4 * 4);
      xs[(q4 * 4 + 0) * 200 + c] = f2b(vv.x);
      xs[(q4 * 4 + 1) * 200 + c] = f2b(vv.y);
      xs[(q4 * 4 + 2) * 200 + c] = f2b(vv.z);
      xs[(q4 * 4 + 3) * 200 + c] = f2b(vv.w);
    }
  }
  __syncthreads();

  #pragma unroll
  for (int i = 0; i < 3; ++i) {
    const int ti = i * 4 + w;
    f32x4 acc[4][4];
    #pragma unroll
    for (int a = 0; a < 4; ++a)
      #pragma unroll
      for (int b = 0; b < 4; ++b) acc[a][b] = zero;

    const unsigned short* wtile = wqkvF + (long)ti * 12288 + lane * 8;
    #pragma unroll
    for (int ks = 0; ks < 6; ++ks) {
      const int kc = ks * 32 + lg * 8;
      bf16x8 a[4], b[4];
      #pragma unroll
      for (int mi = 0; mi < 4; ++mi)
        a[mi] = *(const bf16x8*)(wtile + ks * 2048 + mi * 512);
      #pragma unroll
      for (int ni = 0; ni < 4; ++ni)
        b[ni] = *(const bf16x8*)(xs + (ni * 16 + l15) * 200 + kc);
      #pragma unroll
      for (int mi = 0; mi < 4; ++mi)
        #pragma unroll
        for (int ni = 0; ni < 4; ++ni)
          acc[mi][ni] = MFMA(a[mi], b[ni], acc[mi][ni]);
    }
    unsigned short* dst = (ti < 4) ? qws : (ti < 8) ? kws : vws;
    const int eb = (ti * 64) & 255;
    #pragma unroll
    for (int ni = 0; ni < 4; ++ni) {
      long srow = (long)bi * 3136 + s0 + ni * 16 + l15;
      #pragma unroll
      for (int mi = 0; mi < 4; ++mi) {
        int e0 = eb + mi * 16 + lg * 4;
        uint2 v = {pk2(acc[mi][ni][0], acc[mi][ni][1]),
                   pk2(acc[mi][ni][2], acc[mi][ni][3])};
        *(uint2*)(dst + srow * 256 + e0) = v;
      }
    }
  }
}

// ================= K2: attention core (r16 version) =================
#define PSTRIDE 6272
#define VT_OFF  (4 * PSTRIDE)
#define VTSTRIDE 4608
#define BIAS_LDS (VT_OFF + 4 * VTSTRIDE)
#define LDS_TOT (BIAS_LDS + 2401 * 4)

__global__ __launch_bounds__(256, 4) void attn_core(
    const unsigned short* __restrict__ qws, const unsigned short* __restrict__ kws,
    const unsigned short* __restrict__ vws, const float* __restrict__ bias,
    float* __restrict__ attn_out, unsigned short* __restrict__ o_ws)
{
  __shared__ __align__(16) char lds[LDS_TOT];
  const int tid = threadIdx.x;
  const int w = tid >> 6, lane = tid & 63;
  const int l15 = lane & 15, lg = lane >> 4;
  const int gw = blockIdx.x * 4 + w;
  const int win = gw >> 3, h = gw & 7;
  const int bi = win >> 6, w1 = (win >> 3) & 7, w2 = win & 7;
  const int sw = (w1 * 7) * 56 + w2 * 7;
  const long rowbase = (long)bi * 3136;
  const f32x4 zero = {0.f, 0.f, 0.f, 0.f};

  float* bias_lds = (float*)(lds + BIAS_LDS);
  for (int i = tid; i < 2401; i += 256) bias_lds[i] = bias[i];

  unsigned short* vt = (unsigned short*)(lds + VT_OFF + w * VTSTRIDE);
  {
    #pragma unroll
    for (int pass = 0; pass < 4; ++pass) {
      int t = pass * 16 + (lane >> 2);
      int tc = t < 49 ? t : 48;
      int e8 = (lane & 3) * 8;
      int srow = sw + (tc / 7) * 56 + (tc % 7);
      bf16x8 vv = *(const bf16x8*)(vws + (rowbase + srow) * 256 + h * 32 + e8);
      #pragma unroll
      for (int j = 0; j < 8; ++j) vt[(e8 + j) * 72 + t] = vv[j];
    }
  }
  __syncthreads();

  f32x4 s[4][4];
  {
    const int dc = h * 32 + lg * 8;
    bf16x8 ak[4], bq[4];
    #pragma unroll
    for (int mi = 0; mi < 4; ++mi) {
      int t = mi * 16 + l15; if (t > 48) t = 48;
      int srow = sw + (t / 7) * 56 + (t % 7);
      ak[mi] = *(const bf16x8*)(kws + (rowbase + srow) * 256 + dc);
    }
    #pragma unroll
    for (int ni = 0; ni < 4; ++ni) {
      int t = ni * 16 + l15; if (t > 48) t = 48;
      int srow = sw + (t / 7) * 56 + (t % 7);
      bq[ni] = *(const bf16x8*)(qws + (rowbase + srow) * 256 + dc);
    }
    __builtin_amdgcn_s_setprio(1);
    #pragma unroll
    for (int mi = 0; mi < 4; ++mi)
      #pragma unroll
      for (int ni = 0; ni < 4; ++ni)
        s[mi][ni] = MFMA(ak[mi], bq[ni], zero);
    __builtin_amdgcn_s_setprio(0);
  }

  const float scale = 0.17677669529663687f;
  #pragma unroll
  for (int ni = 0; ni < 4; ++ni) {
    int tq = ni * 16 + l15;
    int tqc = tq < 49 ? tq : 48;
    #pragma unroll
    for (int mi = 0; mi < 4; ++mi)
      #pragma unroll
      for (int r = 0; r < 4; ++r) {
        int tk = mi * 16 + lg * 4 + r;
        float v = s[mi][ni][r];
        s[mi][ni][r] = (tk < 49) ? (v * scale + bias_lds[tqc * 49 + tk]) : -1e30f;
      }
    float m = -1e30f;
    #pragma unroll
    for (int mi = 0; mi < 4; ++mi)
      #pragma unroll
      for (int r = 0; r < 4; ++r) m = fmaxf(m, s[mi][ni][r]);
    m = fmaxf(m, __shfl_xor(m, 16));
    m = fmaxf(m, __shfl_xor(m, 32));
    float sum = 0.f;
    #pragma unroll
    for (int mi = 0; mi < 4; ++mi)
      #pragma unroll
      for (int r = 0; r < 4; ++r) {
        float e = __expf(s[mi][ni][r] - m);
        s[mi][ni][r] = e;
        sum += e;
      }
    sum += __shfl_xor(sum, 16);
    sum += __shfl_xor(sum, 32);
    float inv = 1.0f / sum;
    #pragma unroll
    for (int mi = 0; mi < 4; ++mi)
      #pragma unroll
      for (int r = 0; r < 4; ++r) s[mi][ni][r] *= inv;
  }

  char* pw = lds + w * PSTRIDE;
  #pragma unroll
  for (int ni = 0; ni < 4; ++ni) {
    int tq = ni * 16 + l15;
    if (tq < 49) {
      #pragma unroll
      for (int mi = 0; mi < 4; ++mi) {
        int tk0 = mi * 16 + lg * 4;
        uint2 v = {pk2(s[mi][ni][0], s[mi][ni][1]),
                   pk2(s[mi][ni][2], s[mi][ni][3])};
        *(uint2*)(pw + tq * 128 + ((tk0 * 2) ^ ((tq & 7) << 4))) = v;
      }
    }
  }

  {
    float* abase = attn_out + ((long)win * 8 + h) * 2401;
    #pragma unroll
    for (int it = 0; it < 38; ++it) {
      int f = it * 64 + lane;
      if (f < 2401) {
        int tq = f / 49, tk = f - tq * 49;
        unsigned short pv =
            *(const unsigned short*)(pw + tq * 128 + ((tk * 2) ^ ((tq & 7) << 4)));
        __builtin_nontemporal_store(b2f(pv), abase + f);
      }
    }
  }

  {
    f32x4 o[2][4];
    #pragma unroll
    for (int i = 0; i < 2; ++i)
      #pragma unroll
      for (int j = 0; j < 4; ++j) o[i][j] = zero;
    #pragma unroll
    for (int ks = 0; ks < 2; ++ks) {
      const int tkc = ks * 32 + lg * 8;
      bf16x8 av[2], bp[4];
      #pragma unroll
      for (int mi = 0; mi < 2; ++mi) {
        int e = mi * 16 + l15;
        av[mi] = *(const bf16x8*)(vt + e * 72 + tkc);
      }
      #pragma unroll
      for (int ni = 0; ni < 4; ++ni) {
        int tq = ni * 16 + l15;
        int tqc = tq < 49 ? tq : 48;
        bp[ni] = *(const bf16x8*)(pw + tqc * 128 + ((tkc * 2) ^ ((tqc & 7) << 4)));
      }
      __builtin_amdgcn_s_setprio(1);
      #pragma unroll
      for (int mi = 0; mi < 2; ++mi)
        #pragma unroll
        for (int ni = 0; ni < 4; ++ni)
          o[mi][ni] = MFMA(av[mi], bp[ni], o[mi][ni]);
      __builtin_amdgcn_s_setprio(0);
    }
    unsigned short* ob = o_ws + ((long)win * 8 + h) * 49 * 32;
    #pragma unroll
    for (int mi = 0; mi < 2; ++mi)
      #pragma unroll
      for (int ni = 0; ni < 4; ++ni) {
        int tq = ni * 16 + l15;
        if (tq < 49) {
          int el0 = mi * 16 + lg * 4;
          uint2 v = {pk2(o[mi][ni][0], o[mi][ni][1]),
                     pk2(o[mi][ni][2], o[mi][ni][3])};
          *(uint2*)(ob + tq * 32 + el0) = v;
        }
      }
  }
}

// ================= K3: output projection (r16 version) =================
__global__ __launch_bounds__(256, 8) void out_proj(
    const unsigned short* __restrict__ o_ws, const unsigned short* __restrict__ woF,
    const float* __restrict__ bo, float* __restrict__ out)
{
  __shared__ __align__(16) float obuf[49 * 196];
  const int tid = threadIdx.x;
  const int w = tid >> 6, lane = tid & 63;
  const int l15 = lane & 15, lg = lane >> 4;
  const int win = blockIdx.x;
  const int bi = win >> 6, w1 = (win >> 3) & 7, w2 = win & 7;
  const f32x4 zero = {0.f, 0.f, 0.f, 0.f};

  const unsigned short* wt = woF + (long)(w * 3) * 4096 + lane * 8;

  #pragma unroll
  for (int pass = 0; pass < 2; ++pass) {
    f32x4 acc[3][2];
    #pragma unroll
    for (int j = 0; j < 3; ++j)
      #pragma unroll
      for (int tt = 0; tt < 2; ++tt) acc[j][tt] = zero;

    #pragma unroll
    for (int ks = 0; ks < 8; ++ks) {
      bf16x8 aW[3], bO[2];
      #pragma unroll
      for (int j = 0; j < 3; ++j)
        aW[j] = *(const bf16x8*)(wt + j * 4096 + ks * 512);
      #pragma unroll
      for (int tt = 0; tt < 2; ++tt) {
        int t = (pass * 2 + tt) * 16 + l15;
        int tc = t < 49 ? t : 48;
        bO[tt] = *(const bf16x8*)(o_ws + ((long)(win * 8 + ks) * 49 + tc) * 32 + lg * 8);
      }
      #pragma unroll
      for (int j = 0; j < 3; ++j)
        #pragma unroll
        for (int tt = 0; tt < 2; ++tt)
          acc[j][tt] = MFMA(aW[j], bO[tt], acc[j][tt]);
    }
    #pragma unroll
    for (int j = 0; j < 3; ++j)
      #pragma unroll
      for (int tt = 0; tt < 2; ++tt) {
        int t = (pass * 2 + tt) * 16 + l15;
        if (t < 49) {
          int oc0 = (w * 3 + j) * 16 + lg * 4;
          *(f32x4*)(obuf + t * 196 + oc0) = acc[j][tt];
        }
      }
  }
  __syncthreads();

  const long obase = (long)bi * 602112 + (w1 * 7) * 56 + w2 * 7;
  for (int idx = tid; idx < 192 * 49; idx += 256) {
    int oc = idx / 49, t = idx - oc * 49;
    out[obase + oc * 3136 + (t / 7) * 56 + (t % 7)] = obuf[t * 196 + oc] + bo[oc];
  }
}

extern "C" void kernel_launch(void* const* d_in, const int* in_sizes, int n_in,
                              void* d_out, int out_size, void* d_ws, size_t ws_size,
                              hipStream_t stream)
{
  const float* x    = (const float*)d_in[0];
  const float* mask = (const float*)d_in[1];
  const float* Wq   = (const float*)d_in[2];
  const float* Wkv  = (const float*)d_in[3];
  const float* Wo   = (const float*)d_in[4];
  const float* bo   = (const float*)d_in[5];
  const float* pos  = (const float*)d_in[6];

  float* out  = (float*)d_out;
  float* attn = out + OUT0;

  char* ws = (char*)d_ws;
  unsigned short* o_ws = (unsigned short*)ws;
  unsigned short* qws  = (unsigned short*)(ws + Q_OFF);
  unsigned short* kws  = (unsigned short*)(ws + K_OFF);
  unsigned short* vws  = (unsigned short*)(ws + V_OFF);
  unsigned short* wqkv = (unsigned short*)(ws + WQKV_OFF);
  unsigned short* woF  = (unsigned short*)(ws + WO_OFF);
  float*          bias = (float*)(ws + BIAS_OFF);

  prep<<<778, 256, 0, stream>>>(mask, Wq, Wkv, Wo, pos, wqkv, woF, bias);
  qkv_gemm<<<32 * 49, 256, 0, stream>>>(x, wqkv, qws, kws, vws);
  attn_core<<<4096, 256, 0, stream>>>(qws, kws, vws, bias, attn, o_ws);
  out_proj<<<NWIN, 256, 0, stream>>>(o_ws, woF, bo, out);
}